// Round 10
// baseline (210.661 us; speedup 1.0000x reference)
//
#include <hip/hip_runtime.h>

// CrossAttentionAdapter: softmax over a SINGLETON axis => attn == 1 =>
// out[b,p,:] = (((x@Wm^T+bm)@Wv^T+bv)@Wo_mha^T+bo_mha)@Wo^T+bo, independent of p.
// Pipeline: cvt_xw | G1(+cvt Wv) | G2(+cvt Wo1) | G3(+cvt Wo2) | G4 -> rowf |
// bcast (268 MB sequential). r10: 3 blocks/CU (NBUF=3 ring, 48 KB LDS,
// launch_bounds(256,3)) — r6/r9 showed TLP (waves/SIMD, blocks/CU) is the
// binding lever; ring depth drops to 1-tile prefetch cover, multiplicity
// covers the rest. Counted vmcnt steady wait = 4. T2 swizzle, 1 barrier/tile.

#define BM 64
#define BN 64
#define BK 64
#define NBUF 3

typedef __attribute__((ext_vector_type(8))) __bf16 bf16x8;
typedef __attribute__((ext_vector_type(4))) float f32x4;

__device__ __forceinline__ unsigned short f2bf(float f) {
  unsigned int u = __float_as_uint(f);
  u += 0x7FFFu + ((u >> 16) & 1u);   // RNE
  return (unsigned short)(u >> 16);
}

__device__ __forceinline__ void gload_lds16(const void* g, void* l) {
  __builtin_amdgcn_global_load_lds(
      (const __attribute__((address_space(1))) void*)g,
      (__attribute__((address_space(3))) void*)l, 16, 0, 0);
}

// Convert image (262144 f4) + Wm (524288 f4) -> bf16 at dst.
__global__ __launch_bounds__(256) void cvt_xw(const float* __restrict__ x,
                                              const float* __restrict__ wm,
                                              unsigned short* __restrict__ dst) {
  size_t i = (size_t)blockIdx.x * blockDim.x + threadIdx.x;   // 262144 threads
  for (; i < 786432; i += 262144) {
    const float4 v = (i < 262144)
        ? reinterpret_cast<const float4*>(x)[i]
        : reinterpret_cast<const float4*>(wm)[i - 262144];
    ushort4 o;
    o.x = f2bf(v.x); o.y = f2bf(v.y); o.z = f2bf(v.z); o.w = f2bf(v.w);
    reinterpret_cast<ushort4*>(dst)[i] = o;
  }
}

// C = A (MxK bf16 row-major) * W^T (W: NxK bf16 row-major) + bias, N=2048.
// 64x64 tile, 4 waves (2x2 of 32x32 wave-tiles), 3-deep LDS ring.
// Steady state: tiles t, t+1 in flight (8 loads); wait vmcnt(4) => t landed.
// stage(t+2) issued after the barrier => overwrite of buf (t-1)%3 is safe.
// EPI=0: bf16 store. EPI=1: f32 store (row buffer for bcast kernel).
// CVT: f32->bf16 tail converting the NEXT GEMM's weights.
template <int EPI, bool CVT>
__global__ __launch_bounds__(256, 3) void gemm_bt(
    const unsigned short* __restrict__ A, const unsigned short* __restrict__ W,
    const float* __restrict__ bias, void* __restrict__ outp, int K,
    const float* __restrict__ cvt_src, unsigned short* __restrict__ cvt_dst,
    int cvt_n4) {
  __shared__ __attribute__((aligned(16))) unsigned short As[NBUF][BM * BK];
  __shared__ __attribute__((aligned(16))) unsigned short Bs[NBUF][BN * BK];
  const int tid = threadIdx.x;
  const int lane = tid & 63;
  const int wid = tid >> 6;          // 4 waves, 2x2
  const int rm = (wid >> 1) * 32;    // wave row group
  const int cn = (wid & 1) * 32;     // wave col group
  const int bid = blockIdx.x;
  // bid = [n1 n0 | m3 m2 m1 m0 | x2 x1 x0]; XCD = bid&7 owns 4 N-tiles
  // (256 cols, 1 MB W panel L2-resident across its 16 M-blocks).
  const int bn0 = ((bid & 7) * 4 + (bid >> 7)) * BN;
  const int bm0 = ((bid >> 3) & 15) * BM;
  const int l15 = lane & 15;
  const int l4 = lane >> 4;
  const int lr = lane >> 3;
  const int lc = lane & 7;
  const int scol = ((lc ^ lr) << 3);   // pre-swizzled source col (rule #21)
  const size_t Kz = (size_t)K;

  f32x4 acc[2][2] = {};

  // 4 global_load_lds per wave per stage (2 A-chunks + 2 B-chunks of 8 rows)
  auto stage = [&](int buf, int tile) {
    const int k0 = tile * BK;
#pragma unroll
    for (int j = 0; j < 2; ++j) {
      const int c = wid * 2 + j;                      // chunks 0..7
      gload_lds16(A + (size_t)(bm0 + c * 8 + lr) * Kz + (k0 + scol),
                  &As[buf][c * 512]);
      gload_lds16(W + (size_t)(bn0 + c * 8 + lr) * Kz + (k0 + scol),
                  &Bs[buf][c * 512]);
    }
  };

  auto compute = [&](int buf) {
    const int swz = (l15 & 7) << 3;   // same involution as scol
#pragma unroll
    for (int ks = 0; ks < 2; ++ks) {
      const int kidx = (ks * 32 + l4 * 8) ^ swz;
      bf16x8 a[2], b[2];
#pragma unroll
      for (int mi = 0; mi < 2; ++mi)
        a[mi] = *reinterpret_cast<const bf16x8*>(
            &As[buf][(rm + mi * 16 + l15) * 64 + kidx]);
#pragma unroll
      for (int ni = 0; ni < 2; ++ni)
        b[ni] = *reinterpret_cast<const bf16x8*>(
            &Bs[buf][(cn + ni * 16 + l15) * 64 + kidx]);
      __builtin_amdgcn_s_setprio(1);
#pragma unroll
      for (int mi = 0; mi < 2; ++mi)
#pragma unroll
        for (int ni = 0; ni < 2; ++ni)
          acc[mi][ni] = __builtin_amdgcn_mfma_f32_16x16x32_bf16(
              a[mi], b[ni], acc[mi][ni], 0, 0, 0);
      __builtin_amdgcn_s_setprio(0);
    }
  };

  const int nt = K >> 6;   // 16 or 32
  stage(0, 0); stage(1, 1);          // 8 outstanding / wave
  int b0 = 0, b1 = 1, b2 = 2;        // rotating ring indices (no % in loop)
  int t = 0;
  for (; t < nt - 2; ++t) {
    asm volatile("s_waitcnt vmcnt(4)" ::: "memory");    // tile-t loads landed
    asm volatile("s_waitcnt lgkmcnt(0)" ::: "memory");  // my prior ds_reads done
    __builtin_amdgcn_s_barrier();
    stage(b2, t + 2);   // overwrites buf consumed in compute(t-1): safe
    compute(b0);
    const int tmp = b0; b0 = b1; b1 = b2; b2 = tmp;
  }
  asm volatile("s_waitcnt vmcnt(4) lgkmcnt(0)" ::: "memory");
  __builtin_amdgcn_s_barrier();
  compute(b0); ++t;
  asm volatile("s_waitcnt vmcnt(0) lgkmcnt(0)" ::: "memory");
  __builtin_amdgcn_s_barrier();
  compute(b1);

#pragma unroll
  for (int mi = 0; mi < 2; ++mi)
#pragma unroll
    for (int ni = 0; ni < 2; ++ni) {
      const int col = bn0 + cn + ni * 16 + l15;
      const float bcol = bias[col];
#pragma unroll
      for (int i = 0; i < 4; ++i) {
        const int row = bm0 + rm + mi * 16 + l4 * 4 + i;
        const float v = acc[mi][ni][i] + bcol;
        if (EPI == 0)
          ((unsigned short*)outp)[(size_t)row * 2048 + col] = f2bf(v);
        else
          ((float*)outp)[(size_t)row * 2048 + col] = v;   // rowf (L2-hot)
      }
    }

  if (CVT) {   // convert next GEMM's weights; kernel boundary publishes it
    size_t i = (size_t)bid * 256 + tid;
    for (; i < (size_t)cvt_n4; i += 131072) {
      const float4 v = reinterpret_cast<const float4*>(cvt_src)[i];
      ushort4 o;
      o.x = f2bf(v.x); o.y = f2bf(v.y); o.z = f2bf(v.z); o.w = f2bf(v.w);
      reinterpret_cast<ushort4*>(cvt_dst)[i] = o;
    }
  }
}

// out[b,p,:] = rowf[b,:] for p=0..31. Register-blocked: 1 load, 32 stores.
// Block bid owns row b=bid; thread t owns 2 f32x4 (32 B) of the row; stores
// sweep p. Each wave's store covers 2 KB contiguous; 8 KB per row per p.
__global__ __launch_bounds__(256) void bcast_rows(const f32x4* __restrict__ rowf,
                                                  f32x4* __restrict__ out) {
  const int b = blockIdx.x;
  const int t = threadIdx.x;
  const f32x4 v0 = rowf[(b << 9) | (t << 1)];
  const f32x4 v1 = rowf[(b << 9) | (t << 1) | 1];
  f32x4* ob = out + ((size_t)b << 14) + (t << 1);
#pragma unroll 8
  for (int p = 0; p < 32; ++p) {
    __builtin_nontemporal_store(v0, ob + (size_t)p * 512);
    __builtin_nontemporal_store(v1, ob + (size_t)p * 512 + 1);
  }
}

extern "C" void kernel_launch(void* const* d_in, const int* in_sizes, int n_in,
                              void* d_out, int out_size, void* d_ws, size_t ws_size,
                              hipStream_t stream) {
  const float* image = (const float*)d_in[0];
  const float* Wm   = (const float*)d_in[1];
  const float* bm   = (const float*)d_in[2];
  // d_in[3] prefix_queries: dead (softmax over singleton axis)
  const float* Win  = (const float*)d_in[4];
  const float* bin  = (const float*)d_in[5];
  const float* Wo1  = (const float*)d_in[6];
  const float* bo1  = (const float*)d_in[7];
  const float* Wo2  = (const float*)d_in[8];
  const float* bo2  = (const float*)d_in[9];
  float* out = (float*)d_out;

  const float* Wv = Win + (size_t)2 * 2048 * 2048;
  const float* bv = bin + 2 * 2048;

  unsigned short* wsb = (unsigned short*)d_ws;
  unsigned short* Xb   = wsb;                  // 1M bf16 elems
  unsigned short* Wmb  = wsb + (1u << 20);     // 2M
  unsigned short* Wvb  = wsb + (3u << 20);     // 4M
  unsigned short* W1b  = wsb + (7u << 20);     // 4M
  unsigned short* W2b  = wsb + (11u << 20);    // 4M
  unsigned short* act0 = wsb + (15u << 20);    // 2M
  unsigned short* act1 = wsb + (17u << 20);    // 2M
  unsigned short* act2 = wsb + (19u << 20);    // 2M
  float* rowf = (float*)(wsb + (21u << 20));   // 2M f32 (8 MB)

  cvt_xw<<<1024, 256, 0, stream>>>(image, Wm, wsb);

  gemm_bt<0, true><<<512, 256, 0, stream>>>(Xb, Wmb, bm, act0, 1024,
                                            Wv, Wvb, 1048576);
  gemm_bt<0, true><<<512, 256, 0, stream>>>(act0, Wvb, bv, act1, 2048,
                                            Wo1, W1b, 1048576);
  gemm_bt<0, true><<<512, 256, 0, stream>>>(act1, W1b, bo1, act2, 2048,
                                            Wo2, W2b, 1048576);
  gemm_bt<1, false><<<512, 256, 0, stream>>>(act2, W2b, bo2, rowf, 2048,
                                             nullptr, nullptr, 0);

  bcast_rows<<<1024, 256, 0, stream>>>((const f32x4*)rowf, (f32x4*)out);
  (void)n_in; (void)in_sizes; (void)out_size; (void)ws_size;
}

// Round 11
// 142.585 us; speedup vs baseline: 1.4775x; 1.4775x over previous
//
#include <hip/hip_runtime.h>

// CrossAttentionAdapter: softmax over a SINGLETON axis => attn == 1 =>
// out[b,p,:] = (((x@Wm^T+bm)@Wv^T+bv)@Wo_mha^T+bo_mha)@Wo^T+bo, independent of p.
// Pipeline: cvt_xw | G1(+cvt Wv) | G2(+cvt Wo1) | G3(+cvt Wo2) | G4 + fused
// x32 broadcast (268 MB). GEMM (r9 config — best measured): 64x64 tile,
// 4 waves, 4-deep LDS ring (2-tile prefetch cover, r10 showed 1-tile cover is
// a cliff), counted vmcnt, ONE s_barrier/tile, T2 swizzle via pre-swizzled
// source col (rule #21), 2 blocks/CU (launch_bounds(256,2); r9: TLP lever).

#define BM 64
#define BN 64
#define BK 64
#define NBUF 4

typedef __attribute__((ext_vector_type(8))) __bf16 bf16x8;
typedef __attribute__((ext_vector_type(4))) float f32x4;

__device__ __forceinline__ unsigned short f2bf(float f) {
  unsigned int u = __float_as_uint(f);
  u += 0x7FFFu + ((u >> 16) & 1u);   // RNE
  return (unsigned short)(u >> 16);
}

__device__ __forceinline__ void gload_lds16(const void* g, void* l) {
  __builtin_amdgcn_global_load_lds(
      (const __attribute__((address_space(1))) void*)g,
      (__attribute__((address_space(3))) void*)l, 16, 0, 0);
}

// Convert image (262144 f4) + Wm (524288 f4) -> bf16 at dst.
__global__ __launch_bounds__(256) void cvt_xw(const float* __restrict__ x,
                                              const float* __restrict__ wm,
                                              unsigned short* __restrict__ dst) {
  size_t i = (size_t)blockIdx.x * blockDim.x + threadIdx.x;   // 262144 threads
  for (; i < 786432; i += 262144) {
    const float4 v = (i < 262144)
        ? reinterpret_cast<const float4*>(x)[i]
        : reinterpret_cast<const float4*>(wm)[i - 262144];
    ushort4 o;
    o.x = f2bf(v.x); o.y = f2bf(v.y); o.z = f2bf(v.z); o.w = f2bf(v.w);
    reinterpret_cast<ushort4*>(dst)[i] = o;
  }
}

// C = A (MxK bf16 row-major) * W^T (W: NxK bf16 row-major) + bias, N=2048.
// 64x64 tile, 4 waves (2x2 of 32x32 wave-tiles), 4-deep LDS ring.
// Steady state: tiles t..t+2 in flight (12 loads); wait vmcnt(8) => t landed;
// stage(t+3) after the barrier (all waves past compute(t-1) => overwrite safe).
// EPI=0: bf16 store. EPI=1: fused x32 broadcast — C tile (f32,+bias) -> LDS
// stride 68 -> 32x-replicated nontemporal f32x4 streams (1 KB/instr).
// CVT: f32->bf16 tail converting the NEXT GEMM's weights.
template <int EPI, bool CVT>
__global__ __launch_bounds__(256, 2) void gemm_bt(
    const unsigned short* __restrict__ A, const unsigned short* __restrict__ W,
    const float* __restrict__ bias, void* __restrict__ outp, int K,
    const float* __restrict__ cvt_src, unsigned short* __restrict__ cvt_dst,
    int cvt_n4) {
  __shared__ __attribute__((aligned(16))) unsigned short As[NBUF][BM * BK];
  __shared__ __attribute__((aligned(16))) unsigned short Bs[NBUF][BN * BK];
  const int tid = threadIdx.x;
  const int lane = tid & 63;
  const int wid = tid >> 6;          // 4 waves, 2x2
  const int rm = (wid >> 1) * 32;    // wave row group
  const int cn = (wid & 1) * 32;     // wave col group
  const int bid = blockIdx.x;
  // bid = [n1 n0 | m3 m2 m1 m0 | x2 x1 x0]; XCD = bid&7 owns 4 N-tiles
  // (256 cols, 1 MB W panel L2-resident across its 16 M-blocks).
  const int bn0 = ((bid & 7) * 4 + (bid >> 7)) * BN;
  const int bm0 = ((bid >> 3) & 15) * BM;
  const int l15 = lane & 15;
  const int l4 = lane >> 4;
  const int lr = lane >> 3;
  const int lc = lane & 7;
  const int scol = ((lc ^ lr) << 3);   // pre-swizzled source col (rule #21)
  const size_t Kz = (size_t)K;

  f32x4 acc[2][2] = {};

  // 4 global_load_lds per wave per stage (2 A-chunks + 2 B-chunks of 8 rows)
  auto stage = [&](int buf, int tile) {
    const int k0 = tile * BK;
#pragma unroll
    for (int j = 0; j < 2; ++j) {
      const int c = wid * 2 + j;                      // chunks 0..7
      gload_lds16(A + (size_t)(bm0 + c * 8 + lr) * Kz + (k0 + scol),
                  &As[buf][c * 512]);
      gload_lds16(W + (size_t)(bn0 + c * 8 + lr) * Kz + (k0 + scol),
                  &Bs[buf][c * 512]);
    }
  };

  auto compute = [&](int buf) {
    const int swz = (l15 & 7) << 3;   // same involution as scol
#pragma unroll
    for (int ks = 0; ks < 2; ++ks) {
      const int kidx = (ks * 32 + l4 * 8) ^ swz;
      bf16x8 a[2], b[2];
#pragma unroll
      for (int mi = 0; mi < 2; ++mi)
        a[mi] = *reinterpret_cast<const bf16x8*>(
            &As[buf][(rm + mi * 16 + l15) * 64 + kidx]);
#pragma unroll
      for (int ni = 0; ni < 2; ++ni)
        b[ni] = *reinterpret_cast<const bf16x8*>(
            &Bs[buf][(cn + ni * 16 + l15) * 64 + kidx]);
      __builtin_amdgcn_s_setprio(1);
#pragma unroll
      for (int mi = 0; mi < 2; ++mi)
#pragma unroll
        for (int ni = 0; ni < 2; ++ni)
          acc[mi][ni] = __builtin_amdgcn_mfma_f32_16x16x32_bf16(
              a[mi], b[ni], acc[mi][ni], 0, 0, 0);
      __builtin_amdgcn_s_setprio(0);
    }
  };

  const int nt = K >> 6;   // 16 or 32
  stage(0, 0); stage(1, 1); stage(2, 2);   // 12 outstanding / wave
  int t = 0;
  for (; t < nt - 3; ++t) {
    asm volatile("s_waitcnt vmcnt(8)" ::: "memory");    // tile-t loads landed
    asm volatile("s_waitcnt lgkmcnt(0)" ::: "memory");  // my prior ds_reads done
    __builtin_amdgcn_s_barrier();
    stage((t + 3) & 3, t + 3);   // overwrites buf consumed in compute(t-1): safe
    compute(t & 3);
  }
  asm volatile("s_waitcnt vmcnt(8) lgkmcnt(0)" ::: "memory");
  __builtin_amdgcn_s_barrier();
  compute(t & 3); ++t;
  asm volatile("s_waitcnt vmcnt(4) lgkmcnt(0)" ::: "memory");
  __builtin_amdgcn_s_barrier();
  compute(t & 3); ++t;
  asm volatile("s_waitcnt vmcnt(0) lgkmcnt(0)" ::: "memory");
  __builtin_amdgcn_s_barrier();
  compute(t & 3);

  if (EPI == 0) {
#pragma unroll
    for (int mi = 0; mi < 2; ++mi)
#pragma unroll
      for (int ni = 0; ni < 2; ++ni) {
        const int col = bn0 + cn + ni * 16 + l15;
        const float bcol = bias[col];
#pragma unroll
        for (int i = 0; i < 4; ++i) {
          const int row = bm0 + rm + mi * 16 + l4 * 4 + i;
          ((unsigned short*)outp)[(size_t)row * 2048 + col] =
              f2bf(acc[mi][ni][i] + bcol);
        }
      }
  } else {
    // Fused x32 broadcast. C tile (f32,+bias) -> LDS stride 68, then each
    // wave streams 16 rows x 32 p as f32x4 nontemporal stores (1 KB/instr).
    asm volatile("s_waitcnt lgkmcnt(0)" ::: "memory");
    __builtin_amdgcn_s_barrier();          // all waves done reading As/Bs
    float* Cs = (float*)As;                // 64*68*4 = 17.4 KB of 64 KB
#pragma unroll
    for (int mi = 0; mi < 2; ++mi)
#pragma unroll
      for (int ni = 0; ni < 2; ++ni) {
        const int col = cn + ni * 16 + l15;
        const float bcol = bias[bn0 + col];
#pragma unroll
        for (int i = 0; i < 4; ++i)
          Cs[(rm + mi * 16 + l4 * 4 + i) * 68 + col] = acc[mi][ni][i] + bcol;
      }
    asm volatile("s_waitcnt lgkmcnt(0)" ::: "memory");
    __builtin_amdgcn_s_barrier();
    float* outf = (float*)outp;
    const int c4 = (lane & 15) * 4;        // f32 col within 64-col tile
    const int psub = lane >> 4;            // 4 p-values per instr
#pragma unroll
    for (int it = 0; it < 16; ++it) {
      const int rl = wid * 16 + it;
      const f32x4 v = *reinterpret_cast<const f32x4*>(&Cs[rl * 68 + c4]);
      float* ob = outf + ((size_t)(bm0 + rl) * 32 + psub) * 2048 + bn0 + c4;
#pragma unroll
      for (int pb = 0; pb < 8; ++pb)
        __builtin_nontemporal_store(
            v, reinterpret_cast<f32x4*>(ob + (size_t)pb * 4 * 2048));
    }
  }

  if (CVT) {   // convert next GEMM's weights; kernel boundary publishes it
    size_t i = (size_t)bid * 256 + tid;
    for (; i < (size_t)cvt_n4; i += 131072) {
      const float4 v = reinterpret_cast<const float4*>(cvt_src)[i];
      ushort4 o;
      o.x = f2bf(v.x); o.y = f2bf(v.y); o.z = f2bf(v.z); o.w = f2bf(v.w);
      reinterpret_cast<ushort4*>(cvt_dst)[i] = o;
    }
  }
}

extern "C" void kernel_launch(void* const* d_in, const int* in_sizes, int n_in,
                              void* d_out, int out_size, void* d_ws, size_t ws_size,
                              hipStream_t stream) {
  const float* image = (const float*)d_in[0];
  const float* Wm   = (const float*)d_in[1];
  const float* bm   = (const float*)d_in[2];
  // d_in[3] prefix_queries: dead (softmax over singleton axis)
  const float* Win  = (const float*)d_in[4];
  const float* bin  = (const float*)d_in[5];
  const float* Wo1  = (const float*)d_in[6];
  const float* bo1  = (const float*)d_in[7];
  const float* Wo2  = (const float*)d_in[8];
  const float* bo2  = (const float*)d_in[9];
  float* out = (float*)d_out;

  const float* Wv = Win + (size_t)2 * 2048 * 2048;
  const float* bv = bin + 2 * 2048;

  unsigned short* wsb = (unsigned short*)d_ws;
  unsigned short* Xb   = wsb;                  // 1M bf16 elems
  unsigned short* Wmb  = wsb + (1u << 20);     // 2M
  unsigned short* Wvb  = wsb + (3u << 20);     // 4M
  unsigned short* W1b  = wsb + (7u << 20);     // 4M
  unsigned short* W2b  = wsb + (11u << 20);    // 4M
  unsigned short* act0 = wsb + (15u << 20);    // 2M
  unsigned short* act1 = wsb + (17u << 20);    // 2M
  unsigned short* act2 = wsb + (19u << 20);    // 2M

  cvt_xw<<<1024, 256, 0, stream>>>(image, Wm, wsb);

  gemm_bt<0, true><<<512, 256, 0, stream>>>(Xb, Wmb, bm, act0, 1024,
                                            Wv, Wvb, 1048576);
  gemm_bt<0, true><<<512, 256, 0, stream>>>(act0, Wvb, bv, act1, 2048,
                                            Wo1, W1b, 1048576);
  gemm_bt<0, true><<<512, 256, 0, stream>>>(act1, W1b, bo1, act2, 2048,
                                            Wo2, W2b, 1048576);
  gemm_bt<1, false><<<512, 256, 0, stream>>>(act2, W2b, bo2, out, 2048,
                                             nullptr, nullptr, 0);
  (void)n_in; (void)in_sizes; (void)out_size; (void)ws_size;
}

// Round 12
// 140.389 us; speedup vs baseline: 1.5006x; 1.0156x over previous
//
#include <hip/hip_runtime.h>

// CrossAttentionAdapter: softmax over a SINGLETON axis => attn == 1 =>
// out[b,p,:] = (((x@Wm^T+bm)@Wv^T+bv)@Wo_mha^T+bo_mha)@Wo^T+bo, independent of p.
// Pipeline: cvt_xw | G1(+cvt Wv) | G2(+cvt Wo1) | G3(+cvt Wo2) | G4 + fused
// x32 broadcast (268 MB). GEMM: 64x64 tile, 4 waves, 5-deep LDS ring (3-tile
// in-flight cover, issue-to-use distance 4 — act panels cross XCDs, ~L3
// latency), counted vmcnt, ONE s_barrier/tile, T2 swizzle via pre-swizzled
// source col (rule #21), 2 blocks/CU (80 KB LDS x 2 = exactly 160 KB).
// setprio removed (m190: negative on barrier-synced GEMM).

#define BM 64
#define BN 64
#define BK 64
#define NBUF 5

typedef __attribute__((ext_vector_type(8))) __bf16 bf16x8;
typedef __attribute__((ext_vector_type(4))) float f32x4;

__device__ __forceinline__ unsigned short f2bf(float f) {
  unsigned int u = __float_as_uint(f);
  u += 0x7FFFu + ((u >> 16) & 1u);   // RNE
  return (unsigned short)(u >> 16);
}

__device__ __forceinline__ void gload_lds16(const void* g, void* l) {
  __builtin_amdgcn_global_load_lds(
      (const __attribute__((address_space(1))) void*)g,
      (__attribute__((address_space(3))) void*)l, 16, 0, 0);
}

// Convert image (262144 f4) + Wm (524288 f4) -> bf16 at dst.
__global__ __launch_bounds__(256) void cvt_xw(const float* __restrict__ x,
                                              const float* __restrict__ wm,
                                              unsigned short* __restrict__ dst) {
  size_t i = (size_t)blockIdx.x * blockDim.x + threadIdx.x;   // 262144 threads
  for (; i < 786432; i += 262144) {
    const float4 v = (i < 262144)
        ? reinterpret_cast<const float4*>(x)[i]
        : reinterpret_cast<const float4*>(wm)[i - 262144];
    ushort4 o;
    o.x = f2bf(v.x); o.y = f2bf(v.y); o.z = f2bf(v.z); o.w = f2bf(v.w);
    reinterpret_cast<ushort4*>(dst)[i] = o;
  }
}

// C = A (MxK bf16 row-major) * W^T (W: NxK bf16 row-major) + bias, N=2048.
// 64x64 tile, 4 waves (2x2 of 32x32 wave-tiles), 5-deep LDS ring.
// Steady iter t: tiles t..t+3 in flight (16 loads); wait vmcnt(12) => t
// landed; barrier; stage(t+4) into buf((t+4)%5 == (t-1)%5, consumed at t-1 —
// all waves past it via this barrier); compute(t).
// EPI=0: bf16 store. EPI=1: fused x32 broadcast — C tile (f32,+bias) -> LDS
// stride 68 -> 32x-replicated nontemporal f32x4 streams (1 KB/instr).
// CVT: f32->bf16 tail converting the NEXT GEMM's weights.
template <int EPI, bool CVT>
__global__ __launch_bounds__(256, 2) void gemm_bt(
    const unsigned short* __restrict__ A, const unsigned short* __restrict__ W,
    const float* __restrict__ bias, void* __restrict__ outp, int K,
    const float* __restrict__ cvt_src, unsigned short* __restrict__ cvt_dst,
    int cvt_n4) {
  __shared__ __attribute__((aligned(16))) unsigned short As[NBUF][BM * BK];
  __shared__ __attribute__((aligned(16))) unsigned short Bs[NBUF][BN * BK];
  const int tid = threadIdx.x;
  const int lane = tid & 63;
  const int wid = tid >> 6;          // 4 waves, 2x2
  const int rm = (wid >> 1) * 32;    // wave row group
  const int cn = (wid & 1) * 32;     // wave col group
  const int bid = blockIdx.x;
  // bid = [n1 n0 | m3 m2 m1 m0 | x2 x1 x0]; XCD = bid&7 owns 4 N-tiles
  // (256 cols, 1 MB W panel L2-resident across its 16 M-blocks).
  const int bn0 = ((bid & 7) * 4 + (bid >> 7)) * BN;
  const int bm0 = ((bid >> 3) & 15) * BM;
  const int l15 = lane & 15;
  const int l4 = lane >> 4;
  const int lr = lane >> 3;
  const int lc = lane & 7;
  const int scol = ((lc ^ lr) << 3);   // pre-swizzled source col (rule #21)
  const size_t Kz = (size_t)K;

  f32x4 acc[2][2] = {};

  // 4 global_load_lds per wave per stage (2 A-chunks + 2 B-chunks of 8 rows)
  auto stage = [&](int buf, int tile) {
    const int k0 = tile * BK;
#pragma unroll
    for (int j = 0; j < 2; ++j) {
      const int c = wid * 2 + j;                      // chunks 0..7
      gload_lds16(A + (size_t)(bm0 + c * 8 + lr) * Kz + (k0 + scol),
                  &As[buf][c * 512]);
      gload_lds16(W + (size_t)(bn0 + c * 8 + lr) * Kz + (k0 + scol),
                  &Bs[buf][c * 512]);
    }
  };

  auto compute = [&](int buf) {
    const int swz = (l15 & 7) << 3;   // same involution as scol
#pragma unroll
    for (int ks = 0; ks < 2; ++ks) {
      const int kidx = (ks * 32 + l4 * 8) ^ swz;
      bf16x8 a[2], b[2];
#pragma unroll
      for (int mi = 0; mi < 2; ++mi)
        a[mi] = *reinterpret_cast<const bf16x8*>(
            &As[buf][(rm + mi * 16 + l15) * 64 + kidx]);
#pragma unroll
      for (int ni = 0; ni < 2; ++ni)
        b[ni] = *reinterpret_cast<const bf16x8*>(
            &Bs[buf][(cn + ni * 16 + l15) * 64 + kidx]);
#pragma unroll
      for (int mi = 0; mi < 2; ++mi)
#pragma unroll
        for (int ni = 0; ni < 2; ++ni)
          acc[mi][ni] = __builtin_amdgcn_mfma_f32_16x16x32_bf16(
              a[mi], b[ni], acc[mi][ni], 0, 0, 0);
    }
  };

  const int nt = K >> 6;   // 16 or 32 (both > 4)
  stage(0, 0); stage(1, 1); stage(2, 2); stage(3, 3);   // 16 outstanding/wave
  int b0 = 0, b1 = 1, b2 = 2, b3 = 3, b4 = 4;           // rotating ring
  int t = 0;
  for (; t < nt - 4; ++t) {
    asm volatile("s_waitcnt vmcnt(12)" ::: "memory");   // tile-t loads landed
    asm volatile("s_waitcnt lgkmcnt(0)" ::: "memory");  // my prior ds_reads done
    __builtin_amdgcn_s_barrier();
    stage(b4, t + 4);   // overwrites buf consumed in compute(t-1): safe
    compute(b0);
    const int tmp = b0; b0 = b1; b1 = b2; b2 = b3; b3 = b4; b4 = tmp;
  }
  asm volatile("s_waitcnt vmcnt(12) lgkmcnt(0)" ::: "memory");
  __builtin_amdgcn_s_barrier();
  compute(b0);
  asm volatile("s_waitcnt vmcnt(8) lgkmcnt(0)" ::: "memory");
  __builtin_amdgcn_s_barrier();
  compute(b1);
  asm volatile("s_waitcnt vmcnt(4) lgkmcnt(0)" ::: "memory");
  __builtin_amdgcn_s_barrier();
  compute(b2);
  asm volatile("s_waitcnt vmcnt(0) lgkmcnt(0)" ::: "memory");
  __builtin_amdgcn_s_barrier();
  compute(b3);

  if (EPI == 0) {
#pragma unroll
    for (int mi = 0; mi < 2; ++mi)
#pragma unroll
      for (int ni = 0; ni < 2; ++ni) {
        const int col = bn0 + cn + ni * 16 + l15;
        const float bcol = bias[col];
#pragma unroll
        for (int i = 0; i < 4; ++i) {
          const int row = bm0 + rm + mi * 16 + l4 * 4 + i;
          ((unsigned short*)outp)[(size_t)row * 2048 + col] =
              f2bf(acc[mi][ni][i] + bcol);
        }
      }
  } else {
    // Fused x32 broadcast. C tile (f32,+bias) -> LDS stride 68, then each
    // wave streams 16 rows x 32 p as f32x4 nontemporal stores (1 KB/instr).
    asm volatile("s_waitcnt lgkmcnt(0)" ::: "memory");
    __builtin_amdgcn_s_barrier();          // all waves done reading As/Bs
    float* Cs = (float*)As;                // 64*68*4 = 17.4 KB of 40 KB
#pragma unroll
    for (int mi = 0; mi < 2; ++mi)
#pragma unroll
      for (int ni = 0; ni < 2; ++ni) {
        const int col = cn + ni * 16 + l15;
        const float bcol = bias[bn0 + col];
#pragma unroll
        for (int i = 0; i < 4; ++i)
          Cs[(rm + mi * 16 + l4 * 4 + i) * 68 + col] = acc[mi][ni][i] + bcol;
      }
    asm volatile("s_waitcnt lgkmcnt(0)" ::: "memory");
    __builtin_amdgcn_s_barrier();
    float* outf = (float*)outp;
    const int c4 = (lane & 15) * 4;        // f32 col within 64-col tile
    const int psub = lane >> 4;            // 4 p-values per instr
#pragma unroll
    for (int it = 0; it < 16; ++it) {
      const int rl = wid * 16 + it;
      const f32x4 v = *reinterpret_cast<const f32x4*>(&Cs[rl * 68 + c4]);
      float* ob = outf + ((size_t)(bm0 + rl) * 32 + psub) * 2048 + bn0 + c4;
#pragma unroll
      for (int pb = 0; pb < 8; ++pb)
        __builtin_nontemporal_store(
            v, reinterpret_cast<f32x4*>(ob + (size_t)pb * 4 * 2048));
    }
  }

  if (CVT) {   // convert next GEMM's weights; kernel boundary publishes it
    size_t i = (size_t)bid * 256 + tid;
    for (; i < (size_t)cvt_n4; i += 131072) {
      const float4 v = reinterpret_cast<const float4*>(cvt_src)[i];
      ushort4 o;
      o.x = f2bf(v.x); o.y = f2bf(v.y); o.z = f2bf(v.z); o.w = f2bf(v.w);
      reinterpret_cast<ushort4*>(cvt_dst)[i] = o;
    }
  }
}

extern "C" void kernel_launch(void* const* d_in, const int* in_sizes, int n_in,
                              void* d_out, int out_size, void* d_ws, size_t ws_size,
                              hipStream_t stream) {
  const float* image = (const float*)d_in[0];
  const float* Wm   = (const float*)d_in[1];
  const float* bm   = (const float*)d_in[2];
  // d_in[3] prefix_queries: dead (softmax over singleton axis)
  const float* Win  = (const float*)d_in[4];
  const float* bin  = (const float*)d_in[5];
  const float* Wo1  = (const float*)d_in[6];
  const float* bo1  = (const float*)d_in[7];
  const float* Wo2  = (const float*)d_in[8];
  const float* bo2  = (const float*)d_in[9];
  float* out = (float*)d_out;

  const float* Wv = Win + (size_t)2 * 2048 * 2048;
  const float* bv = bin + 2 * 2048;

  unsigned short* wsb = (unsigned short*)d_ws;
  unsigned short* Xb   = wsb;                  // 1M bf16 elems
  unsigned short* Wmb  = wsb + (1u << 20);     // 2M
  unsigned short* Wvb  = wsb + (3u << 20);     // 4M
  unsigned short* W1b  = wsb + (7u << 20);     // 4M
  unsigned short* W2b  = wsb + (11u << 20);    // 4M
  unsigned short* act0 = wsb + (15u << 20);    // 2M
  unsigned short* act1 = wsb + (17u << 20);    // 2M
  unsigned short* act2 = wsb + (19u << 20);    // 2M

  cvt_xw<<<1024, 256, 0, stream>>>(image, Wm, wsb);

  gemm_bt<0, true><<<512, 256, 0, stream>>>(Xb, Wmb, bm, act0, 1024,
                                            Wv, Wvb, 1048576);
  gemm_bt<0, true><<<512, 256, 0, stream>>>(act0, Wvb, bv, act1, 2048,
                                            Wo1, W1b, 1048576);
  gemm_bt<0, true><<<512, 256, 0, stream>>>(act1, W1b, bo1, act2, 2048,
                                            Wo2, W2b, 1048576);
  gemm_bt<1, false><<<512, 256, 0, stream>>>(act2, W2b, bo2, out, 2048,
                                             nullptr, nullptr, 0);
  (void)n_in; (void)in_sizes; (void)out_size; (void)ws_size;
}